// Round 1
// baseline (351.274 us; speedup 1.0000x reference)
//
#include <hip/hip_runtime.h>
#include <hip/hip_bf16.h>

// LabelWiseMLC: out[b,l] = sigmoid(dot(doc_rep[b,l,:], W[l,:]) + bias[l])
// B=128, L=512, I=1024, all fp32.
// Memory-bound: doc_rep is 256 MiB streamed exactly once. Strategy:
// one 64-lane wave per output element; lane i loads float4 at element
// offset (lane + 64*k)*4B for k=0..3 -> each vector load is a contiguous
// aligned 1 KiB wave-transaction. Shuffle-reduce, bias+sigmoid, store.

#define B_DIM 128
#define L_DIM 512
#define I_DIM 1024

__global__ __launch_bounds__(256) void labelwise_mlc_kernel(
    const float* __restrict__ doc,   // (B, L, I)
    const float* __restrict__ W,     // (L, I)
    const float* __restrict__ bias,  // (L,)
    float* __restrict__ out)         // (B, L)
{
    // global wave id == flat output index (b*L + l)
    const int wave = (blockIdx.x * blockDim.x + threadIdx.x) >> 6;
    const int lane = threadIdx.x & 63;
    const int l = wave & (L_DIM - 1);

    const float4* __restrict__ dp =
        (const float4*)(doc + (size_t)wave * I_DIM);
    const float4* __restrict__ wp =
        (const float4*)(W + (size_t)l * I_DIM);

    float acc = 0.0f;
#pragma unroll
    for (int k = 0; k < 4; ++k) {
        const float4 d = dp[lane + 64 * k];
        const float4 w = wp[lane + 64 * k];
        acc = fmaf(d.x, w.x, acc);
        acc = fmaf(d.y, w.y, acc);
        acc = fmaf(d.z, w.z, acc);
        acc = fmaf(d.w, w.w, acc);
    }

    // 64-lane wave reduction
#pragma unroll
    for (int off = 32; off > 0; off >>= 1)
        acc += __shfl_down(acc, off, 64);

    if (lane == 0) {
        const float v = acc + bias[l];
        out[wave] = 1.0f / (1.0f + __expf(-v));
    }
}

extern "C" void kernel_launch(void* const* d_in, const int* in_sizes, int n_in,
                              void* d_out, int out_size, void* d_ws, size_t ws_size,
                              hipStream_t stream) {
    const float* doc  = (const float*)d_in[0];  // (128, 512, 1024)
    const float* W    = (const float*)d_in[1];  // (512, 1024)
    const float* bias = (const float*)d_in[2];  // (512,)
    float* out = (float*)d_out;                 // (128, 512)

    // 65536 outputs, one wave each, 4 waves per 256-thread block
    const int n_out = B_DIM * L_DIM;
    const int blocks = n_out / 4;  // 16384
    labelwise_mlc_kernel<<<blocks, 256, 0, stream>>>(doc, W, bias, out);
}

// Round 3
// 332.047 us; speedup vs baseline: 1.0579x; 1.0579x over previous
//
#include <hip/hip_runtime.h>
#include <hip/hip_bf16.h>

// LabelWiseMLC: out[b,l] = sigmoid(dot(doc_rep[b,l,:], W[l,:]) + bias[l])
// B=128, L=512, I=1024, all fp32. Memory-bound: doc is 256 MiB streamed once.
//
// Label-stationary waves: each wave owns one label l and WPB=8 batch rows.
// W[l] (4 KiB) is loaded ONCE into 16 VGPRs, reused across 8 dot products
// (cuts W re-reads 16x: 32 MiB vs 256 MiB) and amortizes the shuffle-reduce.
// doc loads are nontemporal (streamed, zero reuse) so they don't evict W
// from L2/L3. 8192 waves = 2048 blocks x 4 waves -> 8 blocks/CU.
//
// Note: __builtin_nontemporal_load needs a NATIVE vector type, not HIP's
// float4 class -> use ext_vector_type(4).

#define B_DIM 128
#define L_DIM 512
#define I_DIM 1024
#define WPB 8  // batch rows per wave

typedef float vfloat4 __attribute__((ext_vector_type(4)));

__global__ __launch_bounds__(256) void labelwise_mlc_kernel(
    const float* __restrict__ doc,   // (B, L, I)
    const float* __restrict__ W,     // (L, I)
    const float* __restrict__ bias,  // (L,)
    float* __restrict__ out)         // (B, L)
{
    const int wave = (blockIdx.x * 256 + threadIdx.x) >> 6;  // 0..8191
    const int lane = threadIdx.x & 63;
    const int l  = wave & (L_DIM - 1);          // label index
    const int b0 = (wave >> 9) * WPB;           // starting batch row

    // W[l] fragment: lane i holds float4s at {i, 64+i, 128+i, 192+i}
    const vfloat4* __restrict__ wp = (const vfloat4*)(W + (size_t)l * I_DIM);
    vfloat4 w[4];
#pragma unroll
    for (int k = 0; k < 4; ++k) w[k] = wp[lane + 64 * k];
    const float bl = bias[l];

#pragma unroll 2
    for (int j = 0; j < WPB; ++j) {
        const int b = b0 + j;
        const vfloat4* __restrict__ dp =
            (const vfloat4*)(doc + ((size_t)b * L_DIM + l) * I_DIM);
        float acc = 0.0f;
#pragma unroll
        for (int k = 0; k < 4; ++k) {
            const vfloat4 d = __builtin_nontemporal_load(dp + lane + 64 * k);
            acc = fmaf(d.x, w[k].x, acc);
            acc = fmaf(d.y, w[k].y, acc);
            acc = fmaf(d.z, w[k].z, acc);
            acc = fmaf(d.w, w[k].w, acc);
        }
        // 64-lane wave reduction
#pragma unroll
        for (int off = 32; off > 0; off >>= 1)
            acc += __shfl_down(acc, off, 64);
        if (lane == 0) {
            const float v = acc + bl;
            out[(size_t)b * L_DIM + l] = 1.0f / (1.0f + __expf(-v));
        }
    }
}

extern "C" void kernel_launch(void* const* d_in, const int* in_sizes, int n_in,
                              void* d_out, int out_size, void* d_ws, size_t ws_size,
                              hipStream_t stream) {
    const float* doc  = (const float*)d_in[0];  // (128, 512, 1024)
    const float* W    = (const float*)d_in[1];  // (512, 1024)
    const float* bias = (const float*)d_in[2];  // (512,)
    float* out = (float*)d_out;                 // (128, 512)

    // 8192 waves total: 512 labels x 16 wave-groups (8 batch rows each)
    const int blocks = (L_DIM * (B_DIM / WPB)) / 4;  // 2048
    labelwise_mlc_kernel<<<blocks, 256, 0, stream>>>(doc, W, bias, out);
}